// Round 1
// baseline (359.520 us; speedup 1.0000x reference)
//
#include <hip/hip_runtime.h>
#include <hip/hip_bf16.h>
#include <stdint.h>

// Problem constants
#define BZc 65536
#define DCc 512
#define NRc 1024

// Tiling
#define BM 128      // rows per workgroup
#define BNC 128     // N chunk
#define BKC 64      // K chunk staged for B
#define A_BYTES (BM * DCc * 2)      // 131072
#define B_BYTES (BNC * BKC * 2)     // 16384
#define SMEM_BYTES (A_BYTES + B_BYTES + 512 + 512 + 512 + 16)  // 149008

typedef __bf16 bf16x8 __attribute__((ext_vector_type(8)));
typedef float f32x4 __attribute__((ext_vector_type(4)));

__device__ __forceinline__ unsigned short f2bf(float f) {
    unsigned int u = __float_as_uint(f);
    return (unsigned short)((u + 0x7FFFu + ((u >> 16) & 1u)) >> 16);  // RNE
}

// ---------------- prep: normalize rel_weight rows -> bf16 in ws; zero out ----------------
__global__ void __launch_bounds__(64) ndl_prep_kernel(const float* __restrict__ rw,
                                                      unsigned short* __restrict__ rwn,
                                                      float* __restrict__ out) {
    if (blockIdx.x == 0 && threadIdx.x == 0) out[0] = 0.0f;
    const int t = threadIdx.x;            // 64 threads, 8 lanes per row, 8 rows/block
    const int row = blockIdx.x * 8 + (t >> 3);
    const int l8 = t & 7;
    const float4* src = (const float4*)(rw + (size_t)row * DCc);
    float4 v[16];
    float ss = 0.0f;
#pragma unroll
    for (int i = 0; i < 16; ++i) {
        v[i] = src[l8 + 8 * i];
        ss += v[i].x * v[i].x + v[i].y * v[i].y + v[i].z * v[i].z + v[i].w * v[i].w;
    }
    ss += __shfl_xor(ss, 1);
    ss += __shfl_xor(ss, 2);
    ss += __shfl_xor(ss, 4);
    const float inv = rsqrtf(fmaxf(ss, 1e-24f));
    ushort4* dst = (ushort4*)(rwn + (size_t)row * DCc);
#pragma unroll
    for (int i = 0; i < 16; ++i) {
        ushort4 u;
        u.x = f2bf(v[i].x * inv); u.y = f2bf(v[i].y * inv);
        u.z = f2bf(v[i].z * inv); u.w = f2bf(v[i].w * inv);
        dst[l8 + 8 * i] = u;
    }
}

// ---------------- main: fused normalize(wo) + bf16-MFMA sim + row max/gather + loss ----------------
__global__ void __launch_bounds__(256) ndl_main_kernel(const float* __restrict__ wo,
                                                       const unsigned short* __restrict__ rwn,
                                                       const long long* __restrict__ iy,
                                                       float* __restrict__ out) {
    extern __shared__ char smem[];
    char* Ab = smem;                                   // [128][512] bf16, XOR-swizzled rows
    char* Bb = smem + A_BYTES;                         // [128][64] bf16, XOR-swizzled rows
    unsigned int* rowmax = (unsigned int*)(smem + A_BYTES + B_BYTES);          // 128 u32
    float* simY = (float*)(smem + A_BYTES + B_BYTES + 512);                    // 128 f32
    int* yv = (int*)(smem + A_BYTES + B_BYTES + 1024);                         // 128 i32
    float* redsum = (float*)(smem + A_BYTES + B_BYTES + 1536);                 // 4 f32

    const int t = threadIdx.x;
    const int rbase = blockIdx.x * BM;

    if (t < BM) {
        rowmax[t] = 0u;            // == encoding of (-2.0 + 2.0) = 0.0f bits
        simY[t] = 0.0f;
        yv[t] = (int)iy[rbase + t];
    }

    // ---- prologue: normalize 128 wo rows into A LDS (bf16, swizzled) ----
    {
        const int l8 = t & 7;
#pragma unroll 1
        for (int p = 0; p < 4; ++p) {
            const int rloc = p * 32 + (t >> 3);
            const float4* src = (const float4*)(wo + (size_t)(rbase + rloc) * DCc);
            float4 v[16];
            float ss = 0.0f;
#pragma unroll
            for (int i = 0; i < 16; ++i) {
                v[i] = src[l8 + 8 * i];
                ss += v[i].x * v[i].x + v[i].y * v[i].y + v[i].z * v[i].z + v[i].w * v[i].w;
            }
            ss += __shfl_xor(ss, 1);
            ss += __shfl_xor(ss, 2);
            ss += __shfl_xor(ss, 4);
            const float inv = rsqrtf(fmaxf(ss, 1e-24f));
            const int swz = (rloc & 7) << 4;
            char* rowp = Ab + rloc * (DCc * 2);
#pragma unroll
            for (int i = 0; i < 16; ++i) {
                ushort4 u;
                u.x = f2bf(v[i].x * inv); u.y = f2bf(v[i].y * inv);
                u.z = f2bf(v[i].z * inv); u.w = f2bf(v[i].w * inv);
                const int boff = ((l8 + 8 * i) * 8) ^ swz;
                *(ushort4*)(rowp + boff) = u;
            }
        }
    }

    const int wid = t >> 6;
    const int lane = t & 63;
    const int wm = wid >> 1;      // wave row half (0..1), 64 rows
    const int wn = wid & 1;       // wave col half (0..1), 64 cols
    const int lm = lane & 15;
    const int lk = lane >> 4;

    int a_rowbase[4], a_swz[4];
#pragma unroll
    for (int mt = 0; mt < 4; ++mt) {
        const int r = wm * 64 + mt * 16 + lm;
        a_rowbase[mt] = r * (DCc * 2);
        a_swz[mt] = (r & 7) << 4;
    }
    int b_rowbase[4], b_swz[4];
#pragma unroll
    for (int nt = 0; nt < 4; ++nt) {
        const int n = wn * 64 + nt * 16 + lm;
        b_rowbase[nt] = n * (BKC * 2);
        b_swz[nt] = (n & 7) << 4;
    }

    for (int nb = 0; nb < 8; ++nb) {
        f32x4 acc[4][4];
#pragma unroll
        for (int mt = 0; mt < 4; ++mt)
#pragma unroll
            for (int nt = 0; nt < 4; ++nt) {
                f32x4 z = {0.0f, 0.0f, 0.0f, 0.0f};
                acc[mt][nt] = z;
            }

        for (int kb = 0; kb < 8; ++kb) {
            __syncthreads();   // previous B chunk fully consumed / prologue done
            // stage B chunk (rows nb*128..+128, k kb*64..+64) -> 16KB, source pre-swizzled
            {
                int4 tmp[4];
#pragma unroll
                for (int it = 0; it < 4; ++it) {
                    const int f = it * 256 + t;               // 16B unit 0..1023
                    const int nloc = f >> 3;
                    const int inner = ((f & 7) << 4) ^ ((nloc & 7) << 4);
                    const char* g = (const char*)rwn +
                        (size_t)(nb * BNC + nloc) * (DCc * 2) + kb * (BKC * 2) + inner;
                    tmp[it] = *(const int4*)g;
                }
#pragma unroll
                for (int it = 0; it < 4; ++it) {
                    const int f = it * 256 + t;
                    *(int4*)(Bb + f * 16) = tmp[it];
                }
            }
            __syncthreads();

#pragma unroll
            for (int kk = 0; kk < 2; ++kk) {
                const int koffA = kb * 128 + kk * 64 + lk * 16;
                const int koffB = kk * 64 + lk * 16;
                bf16x8 af[4], bfr[4];
#pragma unroll
                for (int mt = 0; mt < 4; ++mt)
                    af[mt] = *(const bf16x8*)(Ab + a_rowbase[mt] + (koffA ^ a_swz[mt]));
#pragma unroll
                for (int nt = 0; nt < 4; ++nt)
                    bfr[nt] = *(const bf16x8*)(Bb + b_rowbase[nt] + (koffB ^ b_swz[nt]));
#pragma unroll
                for (int mt = 0; mt < 4; ++mt)
#pragma unroll
                    for (int nt = 0; nt < 4; ++nt)
                        acc[mt][nt] = __builtin_amdgcn_mfma_f32_16x16x32_bf16(
                            af[mt], bfr[nt], acc[mt][nt], 0, 0, 0);
            }
        }

        // epilogue for this N chunk: y-gather + masked row-max
#pragma unroll
        for (int mt = 0; mt < 4; ++mt) {
#pragma unroll
            for (int r = 0; r < 4; ++r) {
                const int mloc = wm * 64 + mt * 16 + lk * 4 + r;
                const int y = yv[mloc];
                float mx = -2.0f;
#pragma unroll
                for (int nt = 0; nt < 4; ++nt) {
                    float s = acc[mt][nt][r];
                    const int nglb = nb * BNC + wn * 64 + nt * 16 + lm;
                    if (nglb == y) { simY[mloc] = s; s = -2.0f; }
                    mx = fmaxf(mx, s);
                }
                mx = fmaxf(mx, __shfl_xor(mx, 1));
                mx = fmaxf(mx, __shfl_xor(mx, 2));
                mx = fmaxf(mx, __shfl_xor(mx, 4));
                mx = fmaxf(mx, __shfl_xor(mx, 8));
                if (lm == 0)
                    atomicMax(&rowmax[mloc], __float_as_uint(mx + 2.0f));  // mx+2 > 0: bits monotone
            }
        }
    }

    __syncthreads();
    float c = 0.0f;
    if (t < BM) {
        const float ms = __uint_as_float(rowmax[t]) - 2.0f;
        const float sy = simY[t];
        const float pos = sqrtf(fmaxf(2.0f - 2.0f * sy, 0.0f));
        const float neg = sqrtf(fmaxf(2.0f - 2.0f * ms, 0.0f));
        c = pos + fminf(fmaxf(1.0f - neg, 0.0f), 9999.0f);
    }
    c += __shfl_xor(c, 1);
    c += __shfl_xor(c, 2);
    c += __shfl_xor(c, 4);
    c += __shfl_xor(c, 8);
    c += __shfl_xor(c, 16);
    c += __shfl_xor(c, 32);
    if (lane == 0) redsum[wid] = c;
    __syncthreads();
    if (t == 0) {
        const float tot = redsum[0] + redsum[1] + redsum[2] + redsum[3];
        atomicAdd(out, tot * (1.0f / (float)BZc));
    }
}

extern "C" void kernel_launch(void* const* d_in, const int* in_sizes, int n_in,
                              void* d_out, int out_size, void* d_ws, size_t ws_size,
                              hipStream_t stream) {
    const float* wo = (const float*)d_in[0];
    const float* rw = (const float*)d_in[1];
    const long long* iy = (const long long*)d_in[2];
    float* out = (float*)d_out;
    unsigned short* rwn = (unsigned short*)d_ws;   // 1024*512 bf16 = 1 MB

    // allow >64KB dynamic LDS (ignore error if not needed)
    (void)hipFuncSetAttribute(reinterpret_cast<const void*>(ndl_main_kernel),
                              hipFuncAttributeMaxDynamicSharedMemorySize, SMEM_BYTES);

    ndl_prep_kernel<<<NRc / 8, 64, 0, stream>>>(rw, rwn, out);
    ndl_main_kernel<<<BZc / BM, 256, SMEM_BYTES, stream>>>(wo, rwn, iy, out);
}

// Round 3
// 290.099 us; speedup vs baseline: 1.2393x; 1.2393x over previous
//
#include <hip/hip_runtime.h>
#include <stdint.h>

#define BZc 65536
#define DCc 512
#define NRc 1024
#define BM 64
#define NCHUNK 128          // 8 nb * 16 kb
#define BCH 4096            // one B chunk [128 n][32 k] fp8

typedef float f32x4 __attribute__((ext_vector_type(4)));
typedef const unsigned int __attribute__((address_space(1)))* gas1_t;
typedef unsigned int __attribute__((address_space(3)))* las3_t;

// ---------------- prep: normalize rel_weight -> fp8 e4m3, pre-swizzled (bits 3-4 ^ ((n>>2)&3)<<3); zero out ----
__global__ void __launch_bounds__(64) ndl_prep(const float* __restrict__ rw,
                                               unsigned char* __restrict__ rwn,
                                               float* __restrict__ out) {
    if (blockIdx.x == 0 && threadIdx.x == 0) out[0] = 0.0f;
    const int t = threadIdx.x;
    const int row = blockIdx.x * 8 + (t >> 3);
    const int l8 = t & 7;                     // 8 lanes/row, 64 consecutive floats each
    const float4* src = (const float4*)(rw + (size_t)row * DCc) + l8 * 16;
    float4 v[16];
    float ss = 0.0f;
#pragma unroll
    for (int i = 0; i < 16; ++i) {
        v[i] = src[i];
        ss += v[i].x*v[i].x + v[i].y*v[i].y + v[i].z*v[i].z + v[i].w*v[i].w;
    }
    ss += __shfl_xor(ss, 1);
    ss += __shfl_xor(ss, 2);
    ss += __shfl_xor(ss, 4);
    const float inv = rsqrtf(fmaxf(ss, 1e-24f));
    const int swz = ((row >> 2) & 3) << 3;
    char* rowp = (char*)rwn + (size_t)row * DCc;
#pragma unroll
    for (int g = 0; g < 8; ++g) {
        int lo = __builtin_amdgcn_cvt_pk_fp8_f32(v[2*g].x*inv,   v[2*g].y*inv,   0,  false);
        lo     = __builtin_amdgcn_cvt_pk_fp8_f32(v[2*g].z*inv,   v[2*g].w*inv,   lo, true);
        int hi = __builtin_amdgcn_cvt_pk_fp8_f32(v[2*g+1].x*inv, v[2*g+1].y*inv, 0,  false);
        hi     = __builtin_amdgcn_cvt_pk_fp8_f32(v[2*g+1].z*inv, v[2*g+1].w*inv, hi, true);
        int2 pk; pk.x = lo; pk.y = hi;
        *(int2*)(rowp + ((l8 * 64 + g * 8) ^ swz)) = pk;
    }
}

// ---------------- main ----------------
__global__ void __launch_bounds__(256, 3) ndl_main(const float* __restrict__ wo,
                                                   const unsigned char* __restrict__ rwn,
                                                   const long long* __restrict__ iy,
                                                   float* __restrict__ out) {
    __shared__ char As[BM * DCc];        // 32KB [64][512] fp8, byte ^ ((r&15)<<3)
    __shared__ char Bs[4 * BCH];         // 16KB quad-buffered chunks
    __shared__ float invn[BM];
    __shared__ float mxs[BM];
    __shared__ float sys[BM];
    __shared__ float redsum[4];

    const int t = threadIdx.x;
    const int wid = t >> 6;
    const int lane = t & 63;
    const int lm = lane & 15;
    const int lk = lane >> 4;
    const int wm = wid >> 1;      // M half (32 rows)
    const int wn = wid & 1;       // N half (64 cols of the 128-col chunk)
    const int rbase = blockIdx.x * BM;

    // y indices for this lane's C rows (row = wm*32 + mt*16 + lk*4 + r)
    int yrow[2][4];
#pragma unroll
    for (int mt = 0; mt < 2; ++mt)
#pragma unroll
        for (int r = 0; r < 4; ++r)
            yrow[mt][r] = (int)iy[rbase + wm*32 + mt*16 + lk*4 + r];

    // ---- A prologue: 64 rows x 512 f32 -> raw fp8 swizzled LDS + inv-norms ----
    {
        const int r = t >> 2;
        const int q = t & 3;
        const float* src = wo + (size_t)(rbase + r) * DCc + q * 128;
        const int swz = (r & 15) << 3;
        char* rowp = As + r * DCc;
        float ss = 0.0f;
#pragma unroll
        for (int g = 0; g < 16; ++g) {
            float4 v0 = *(const float4*)(src + g * 8);
            float4 v1 = *(const float4*)(src + g * 8 + 4);
            ss += v0.x*v0.x + v0.y*v0.y + v0.z*v0.z + v0.w*v0.w
                + v1.x*v1.x + v1.y*v1.y + v1.z*v1.z + v1.w*v1.w;
            int lo = __builtin_amdgcn_cvt_pk_fp8_f32(v0.x, v0.y, 0,  false);
            lo     = __builtin_amdgcn_cvt_pk_fp8_f32(v0.z, v0.w, lo, true);
            int hi = __builtin_amdgcn_cvt_pk_fp8_f32(v1.x, v1.y, 0,  false);
            hi     = __builtin_amdgcn_cvt_pk_fp8_f32(v1.z, v1.w, hi, true);
            int2 pk; pk.x = lo; pk.y = hi;
            *(int2*)(rowp + ((q * 128 + g * 8) ^ swz)) = pk;
        }
        ss += __shfl_xor(ss, 1);
        ss += __shfl_xor(ss, 2);
        if (q == 0) invn[r] = rsqrtf(fmaxf(ss, 1e-24f));
    }
    __syncthreads();

    // per-lane constant addresses
    const int r0 = wm*32 + lm;
    const int r1 = wm*32 + 16 + lm;
    const int arow0 = r0 * DCc, aswz0 = (r0 & 15) << 3;
    const int arow1 = r1 * DCc, aswz1 = (r1 & 15) << 3;
    int boff[4];
#pragma unroll
    for (int nt = 0; nt < 4; ++nt) {
        const int n = wn*64 + nt*16 + lm;
        boff[nt] = n * 32 + ((lk * 8) ^ (((n >> 2) & 3) << 3));
    }
    // B staging source: per-lane addr; dst = uniform base + lane*16
    const unsigned char* bsrc = rwn + (size_t)((wid*32 + (lane >> 1)) * DCc + (lane & 1) * 16);
    char* bdst = Bs + wid * 1024;

#define ISSUE_B(C) do {                                                          \
        const int c_ = (C) & (NCHUNK - 1);                                       \
        __builtin_amdgcn_global_load_lds(                                        \
            (gas1_t)(bsrc + ((c_ >> 4) << 16) + ((c_ & 15) << 5)),               \
            (las3_t)(bdst + (c_ & 3) * BCH), 16, 0, 0);                          \
    } while (0)

    ISSUE_B(0); ISSUE_B(1); ISSUE_B(2);

    f32x4 acc[2][4];
    float mx[2][4], sy[2][4];
#pragma unroll
    for (int mt = 0; mt < 2; ++mt)
#pragma unroll
        for (int nt = 0; nt < 4; ++nt) { f32x4 z = {0.f,0.f,0.f,0.f}; acc[mt][nt] = z; }
#pragma unroll
    for (int mt = 0; mt < 2; ++mt)
#pragma unroll
        for (int r = 0; r < 4; ++r) { mx[mt][r] = -1e30f; sy[mt][r] = -1e30f; }

    for (int c = 0; c < NCHUNK; ++c) {
        // my ds_reads of prev chunk sampled + my load of chunk c arrived
        asm volatile("s_waitcnt vmcnt(2) lgkmcnt(0)" ::: "memory");
        __builtin_amdgcn_s_barrier();
        __builtin_amdgcn_sched_barrier(0);
        ISSUE_B(c + 3);

        const int kt = c & 15;
        const char* bb = Bs + (c & 3) * BCH;
        const int ka = kt * 32 + lk * 8;
        unsigned long long a0 = *(const unsigned long long*)(As + arow0 + (ka ^ aswz0));
        unsigned long long a1 = *(const unsigned long long*)(As + arow1 + (ka ^ aswz1));
        unsigned long long b0 = *(const unsigned long long*)(bb + boff[0]);
        unsigned long long b1 = *(const unsigned long long*)(bb + boff[1]);
        unsigned long long b2 = *(const unsigned long long*)(bb + boff[2]);
        unsigned long long b3 = *(const unsigned long long*)(bb + boff[3]);
        acc[0][0] = __builtin_amdgcn_mfma_f32_16x16x32_fp8_fp8(a0, b0, acc[0][0], 0, 0, 0);
        acc[0][1] = __builtin_amdgcn_mfma_f32_16x16x32_fp8_fp8(a0, b1, acc[0][1], 0, 0, 0);
        acc[0][2] = __builtin_amdgcn_mfma_f32_16x16x32_fp8_fp8(a0, b2, acc[0][2], 0, 0, 0);
        acc[0][3] = __builtin_amdgcn_mfma_f32_16x16x32_fp8_fp8(a0, b3, acc[0][3], 0, 0, 0);
        acc[1][0] = __builtin_amdgcn_mfma_f32_16x16x32_fp8_fp8(a1, b0, acc[1][0], 0, 0, 0);
        acc[1][1] = __builtin_amdgcn_mfma_f32_16x16x32_fp8_fp8(a1, b1, acc[1][1], 0, 0, 0);
        acc[1][2] = __builtin_amdgcn_mfma_f32_16x16x32_fp8_fp8(a1, b2, acc[1][2], 0, 0, 0);
        acc[1][3] = __builtin_amdgcn_mfma_f32_16x16x32_fp8_fp8(a1, b3, acc[1][3], 0, 0, 0);

        if (kt == 15) {
            const int nb = c >> 4;
#pragma unroll
            for (int mt = 0; mt < 2; ++mt)
#pragma unroll
                for (int nt = 0; nt < 4; ++nt) {
                    const int nglb = nb*128 + wn*64 + nt*16 + lm;
#pragma unroll
                    for (int r = 0; r < 4; ++r) {
                        float s = acc[mt][nt][r];
                        if (nglb == yrow[mt][r]) { sy[mt][r] = s; s = -1e30f; }
                        mx[mt][r] = fmaxf(mx[mt][r], s);
                    }
                    f32x4 z = {0.f,0.f,0.f,0.f};
                    acc[mt][nt] = z;
                }
        }
    }
    asm volatile("s_waitcnt vmcnt(0)" ::: "memory");

    // reduce over the 16 column-lanes
#pragma unroll
    for (int d = 1; d <= 8; d <<= 1)
#pragma unroll
        for (int mt = 0; mt < 2; ++mt)
#pragma unroll
            for (int r = 0; r < 4; ++r) {
                mx[mt][r] = fmaxf(mx[mt][r], __shfl_xor(mx[mt][r], d));
                sy[mt][r] = fmaxf(sy[mt][r], __shfl_xor(sy[mt][r], d));
            }
    // combine the two N-half waves via LDS
    if (wn == 0 && lm == 0) {
#pragma unroll
        for (int mt = 0; mt < 2; ++mt)
#pragma unroll
            for (int r = 0; r < 4; ++r) {
                const int row = wm*32 + mt*16 + lk*4 + r;
                mxs[row] = mx[mt][r];
                sys[row] = sy[mt][r];
            }
    }
    __syncthreads();
    float csum = 0.0f;
    if (wn == 1 && lm == 0) {
#pragma unroll
        for (int mt = 0; mt < 2; ++mt)
#pragma unroll
            for (int r = 0; r < 4; ++r) {
                const int row = wm*32 + mt*16 + lk*4 + r;
                const float inva = invn[row];
                const float ms  = fmaxf(mx[mt][r], mxs[row]) * inva;
                const float syv = fmaxf(sy[mt][r], sys[row]) * inva;
                const float pos = sqrtf(fmaxf(2.0f - 2.0f * syv, 0.0f));
                const float neg = sqrtf(fmaxf(2.0f - 2.0f * ms, 0.0f));
                csum += pos + fminf(fmaxf(1.0f - neg, 0.0f), 9999.0f);
            }
    }
#pragma unroll
    for (int d = 1; d <= 32; d <<= 1) csum += __shfl_xor(csum, d);
    if (lane == 0) redsum[wid] = csum;
    __syncthreads();
    if (t == 0)
        atomicAdd(out, (redsum[0] + redsum[1] + redsum[2] + redsum[3]) * (1.0f / (float)BZc));
}

extern "C" void kernel_launch(void* const* d_in, const int* in_sizes, int n_in,
                              void* d_out, int out_size, void* d_ws, size_t ws_size,
                              hipStream_t stream) {
    const float* wo = (const float*)d_in[0];
    const float* rw = (const float*)d_in[1];
    const long long* iy = (const long long*)d_in[2];
    float* out = (float*)d_out;
    unsigned char* rwn = (unsigned char*)d_ws;   // 1024*512 fp8 = 512KB

    ndl_prep<<<NRc / 8, 64, 0, stream>>>(rw, rwn, out);
    ndl_main<<<BZc / BM, 256, 0, stream>>>(wo, rwn, iy, out);
}